// Round 1
// baseline (2189.349 us; speedup 1.0000x reference)
//
#include <hip/hip_runtime.h>
#include <math.h>

#define B_    8
#define N_    1025
#define H_    12
#define HD_   64
#define C_    768
#define BH_   (B_*H_)
#define NTOK  (B_*N_)          // 8200
#define SCALE 0.125f

// ws layout (floats)
#define QKV_ELEMS (BH_*N_*HD_)         // 6,297,600
#define Q_OFF   0
#define K_OFF   (QKV_ELEMS)
#define V_OFF   (2*QKV_ELEMS)
#define AO_OFF  (3*QKV_ELEMS)          // attn out, (B,N,C) = same elem count
#define BUCKET_BYTE_OFF ((size_t)4*QKV_ELEMS*4)   // ~100.8 MB in

// ---------------- bucket table (static, matches numpy float64 exactly) ----------------
__global__ void bucket_kernel(unsigned char* __restrict__ bucket) {
    int tid = blockIdx.x * 256 + threadIdx.x;
    if (tid >= N_ * N_) return;
    int i = tid / N_, j = tid % N_;
    int bk;
    if (i < 1 || j < 1) {
        bk = 7;                                   // cls-token bucket
    } else {
        int pi = i - 1, pj = j - 1;
        int dy = (pi >> 5) - (pj >> 5);
        int dx = (pi & 31) - (pj & 31);
        double dis = rint(sqrt((double)(dy*dy + dx*dx)));
        if (dis <= 1.9) {
            bk = (int)dis;                        // 0 or 1
        } else {
            double t = 1.9 + log(dis / 1.9) / log(15.2 / 1.9) * (3.8 - 1.9);
            double r = rint(t);
            if (r > 3.8) r = 3.8;
            bk = (int)r;                          // 2 or 3
        }
    }
    bucket[tid] = (unsigned char)bk;
}

// ---------------- QKV GEMM: out = x(8200x768) @ qkv_w^T(768x2304) ----------------
// 128x128 tile, K-tile 16, 8x8 microtile, k-major LDS
__global__ __launch_bounds__(256) void qkv_kernel(
        const float* __restrict__ x, const float* __restrict__ w,
        float* __restrict__ qb, float* __restrict__ kb, float* __restrict__ vb) {
    __shared__ float As[16][132];
    __shared__ float Bs[16][132];
    const int m0 = blockIdx.x * 128;
    const int c0 = blockIdx.y * 128;
    const int t  = threadIdx.x;
    const int ty = t >> 4, tx = t & 15;

    float acc[8][8];
#pragma unroll
    for (int i = 0; i < 8; i++)
#pragma unroll
        for (int j = 0; j < 8; j++) acc[i][j] = 0.f;

    for (int k0 = 0; k0 < C_; k0 += 16) {
        __syncthreads();
#pragma unroll
        for (int l = 0; l < 2; l++) {
            int row = l * 64 + (t >> 2);
            int k4  = (t & 3) * 4;
            float4 av = make_float4(0.f, 0.f, 0.f, 0.f);
            int m = m0 + row;
            if (m < NTOK) av = *(const float4*)(x + (size_t)m * C_ + k0 + k4);
            As[k4+0][row] = av.x; As[k4+1][row] = av.y;
            As[k4+2][row] = av.z; As[k4+3][row] = av.w;
            float4 bv = *(const float4*)(w + (size_t)(c0 + row) * C_ + k0 + k4);
            Bs[k4+0][row] = bv.x; Bs[k4+1][row] = bv.y;
            Bs[k4+2][row] = bv.z; Bs[k4+3][row] = bv.w;
        }
        __syncthreads();
#pragma unroll
        for (int kk = 0; kk < 16; kk++) {
            float a[8], b[8];
            *(float4*)(a)     = *(float4*)&As[kk][ty*8];
            *(float4*)(a + 4) = *(float4*)&As[kk][ty*8 + 4];
            *(float4*)(b)     = *(float4*)&Bs[kk][tx*8];
            *(float4*)(b + 4) = *(float4*)&Bs[kk][tx*8 + 4];
#pragma unroll
            for (int i = 0; i < 8; i++)
#pragma unroll
                for (int j = 0; j < 8; j++) acc[i][j] += a[i] * b[j];
        }
    }

    // epilogue: scatter to q/k/v in (b*H+h, n, d) layout; 8 cols of a thread share comp/h
    int cb   = c0 + tx * 8;
    int comp = cb / C_;
    int rem  = cb % C_;
    int h    = rem >> 6, d0 = rem & 63;
    float* dst = (comp == 0) ? qb : ((comp == 1) ? kb : vb);
    float sc = (comp == 0) ? SCALE : 1.0f;
#pragma unroll
    for (int i = 0; i < 8; i++) {
        int m = m0 + ty * 8 + i;
        if (m >= NTOK) break;
        unsigned um = (unsigned)m;
        int b = um / (unsigned)N_, n = um % (unsigned)N_;
        float* p = dst + ((size_t)((b * H_ + h) * N_ + n)) * HD_ + d0;
        float4 v0 = make_float4(acc[i][0]*sc, acc[i][1]*sc, acc[i][2]*sc, acc[i][3]*sc);
        float4 v1 = make_float4(acc[i][4]*sc, acc[i][5]*sc, acc[i][6]*sc, acc[i][7]*sc);
        *(float4*)p       = v0;
        *(float4*)(p + 4) = v1;
    }
}

// ---------------- attention: flash-style, 32-row Q tile, online softmax ----------------
__global__ __launch_bounds__(256) void attn_kernel(
        const float* __restrict__ qb, const float* __restrict__ kb,
        const float* __restrict__ vb, const float* __restrict__ rpe,
        const unsigned char* __restrict__ bucket, float* __restrict__ ao) {
    __shared__ float Qs[32][68];
    __shared__ float Ks[32][68];
    __shared__ float Vs[32][68];
    __shared__ float Ss[32][33];
    __shared__ float lut[32][8];
    __shared__ float red[32][8];
    __shared__ float mrow[32], lrow[32], arow[32];

    const int it = blockIdx.x;          // 0..32
    const int bh = blockIdx.y;          // 0..95
    const int b  = bh / H_, h = bh % H_;
    const int i0 = it * 32;
    const int t  = threadIdx.x;
    const float* qp = qb + (size_t)bh * N_ * HD_;
    const float* kp = kb + (size_t)bh * N_ * HD_;
    const float* vp = vb + (size_t)bh * N_ * HD_;

    // load Q tile (zeros past N)
#pragma unroll
    for (int l = 0; l < 2; l++) {
        int f = l * 256 + t;
        int row = f >> 4, d4 = (f & 15) * 4;
        float4 qv = make_float4(0.f, 0.f, 0.f, 0.f);
        if (i0 + row < N_) qv = *(const float4*)(qp + (size_t)(i0 + row) * HD_ + d4);
        *(float4*)&Qs[row][d4] = qv;
    }
    if (t < 32) { mrow[t] = -INFINITY; lrow[t] = 0.f; }
    __syncthreads();

    // per-row 8-bucket bias LUT: lut[r][m] = q_i . rpe_w[:,m]
    {
        int r = t >> 3, m = t & 7;
        float s = 0.f;
#pragma unroll
        for (int d = 0; d < 64; d++) s += Qs[r][d] * rpe[d * 8 + m];
        lut[r][m] = s;
    }

    float o[8];
#pragma unroll
    for (int u = 0; u < 8; u++) o[u] = 0.f;
    const int tr = t >> 4, tc = t & 15;    // S-compute mapping (2x2 of 32x32)
    const int rr = t >> 3, g  = t & 7;     // softmax / PV mapping

    for (int j0 = 0; j0 < N_; j0 += 32) {
        __syncthreads();   // previous PV done; also covers lut on first iter
        // load K/V tile (zeros past N)
#pragma unroll
        for (int l = 0; l < 2; l++) {
            int f = l * 256 + t;
            int row = f >> 4, d4 = (f & 15) * 4;
            float4 kv = make_float4(0.f, 0.f, 0.f, 0.f);
            float4 vv = make_float4(0.f, 0.f, 0.f, 0.f);
            if (j0 + row < N_) {
                kv = *(const float4*)(kp + (size_t)(j0 + row) * HD_ + d4);
                vv = *(const float4*)(vp + (size_t)(j0 + row) * HD_ + d4);
            }
            *(float4*)&Ks[row][d4] = kv;
            *(float4*)&Vs[row][d4] = vv;
        }
        __syncthreads();

        // S = Q K^T (+bias, mask)
        float s00 = 0.f, s01 = 0.f, s10 = 0.f, s11 = 0.f;
#pragma unroll
        for (int d4 = 0; d4 < 64; d4 += 4) {
            float4 q0 = *(float4*)&Qs[tr][d4];
            float4 q1 = *(float4*)&Qs[tr + 16][d4];
            float4 k0 = *(float4*)&Ks[tc][d4];
            float4 k1 = *(float4*)&Ks[tc + 16][d4];
            s00 += q0.x*k0.x + q0.y*k0.y + q0.z*k0.z + q0.w*k0.w;
            s01 += q0.x*k1.x + q0.y*k1.y + q0.z*k1.z + q0.w*k1.w;
            s10 += q1.x*k0.x + q1.y*k0.y + q1.z*k0.z + q1.w*k0.w;
            s11 += q1.x*k1.x + q1.y*k1.y + q1.z*k1.z + q1.w*k1.w;
        }
        {
            int i_a = i0 + tr, i_b = i0 + tr + 16;
            int j_a = j0 + tc, j_b = j0 + tc + 16;
            s00 = (i_a < N_ && j_a < N_) ? s00 + lut[tr   ][bucket[(size_t)i_a * N_ + j_a]] : -INFINITY;
            s01 = (i_a < N_ && j_b < N_) ? s01 + lut[tr   ][bucket[(size_t)i_a * N_ + j_b]] : -INFINITY;
            s10 = (i_b < N_ && j_a < N_) ? s10 + lut[tr+16][bucket[(size_t)i_b * N_ + j_a]] : -INFINITY;
            s11 = (i_b < N_ && j_b < N_) ? s11 + lut[tr+16][bucket[(size_t)i_b * N_ + j_b]] : -INFINITY;
        }
        Ss[tr][tc]           = s00;
        Ss[tr][tc + 16]      = s01;
        Ss[tr + 16][tc]      = s10;
        Ss[tr + 16][tc + 16] = s11;
        __syncthreads();

        // row-max partials
        {
            float mp = -INFINITY;
#pragma unroll
            for (int jj = 0; jj < 4; jj++) mp = fmaxf(mp, Ss[rr][g * 4 + jj]);
            red[rr][g] = mp;
        }
        __syncthreads();
        if (t < 32) {
            float mn = mrow[t];
#pragma unroll
            for (int u = 0; u < 8; u++) mn = fmaxf(mn, red[t][u]);
            arow[t] = __expf(mrow[t] - mn);   // 0 on first tile (mrow = -inf)
            mrow[t] = mn;
        }
        __syncthreads();

        // P = exp(S-m), partial sums, rescale O
        {
            float mn = mrow[rr];
            float sum = 0.f;
#pragma unroll
            for (int jj = 0; jj < 4; jj++) {
                int j = g * 4 + jj;
                float p = __expf(Ss[rr][j] - mn);   // masked (-inf) -> 0
                Ss[rr][j] = p;
                sum += p;
            }
            red[rr][g] = sum;
            float al = arow[rr];
#pragma unroll
            for (int u = 0; u < 8; u++) o[u] *= al;
        }
        __syncthreads();
        if (t < 32) {
            float s = 0.f;
#pragma unroll
            for (int u = 0; u < 8; u++) s += red[t][u];
            lrow[t] = lrow[t] * arow[t] + s;
        }
        // PV accumulate: thread (rr, dg=g) owns O[rr][g*8 .. g*8+7]
        {
#pragma unroll 4
            for (int j = 0; j < 32; j++) {
                float p = Ss[rr][j];
                float4 v0 = *(float4*)&Vs[j][g * 8];
                float4 v1 = *(float4*)&Vs[j][g * 8 + 4];
                o[0] += p * v0.x; o[1] += p * v0.y; o[2] += p * v0.z; o[3] += p * v0.w;
                o[4] += p * v1.x; o[5] += p * v1.y; o[6] += p * v1.z; o[7] += p * v1.w;
            }
        }
    }
    __syncthreads();   // lrow final values visible
    {
        int i = i0 + rr;
        if (i < N_) {
            float inv = 1.0f / lrow[rr];
            float4 r0 = make_float4(o[0]*inv, o[1]*inv, o[2]*inv, o[3]*inv);
            float4 r1 = make_float4(o[4]*inv, o[5]*inv, o[6]*inv, o[7]*inv);
            float* p = ao + ((size_t)(b * N_ + i)) * C_ + h * HD_ + g * 8;
            *(float4*)p       = r0;
            *(float4*)(p + 4) = r1;
        }
    }
}

// ---------------- proj GEMM: out = ao(8200x768) @ proj_w^T(768x768) + proj_b ----------------
__global__ __launch_bounds__(256) void proj_kernel(
        const float* __restrict__ a, const float* __restrict__ w,
        const float* __restrict__ bias, float* __restrict__ out) {
    __shared__ float As[16][132];
    __shared__ float Bs[16][132];
    const int m0 = blockIdx.x * 128;
    const int c0 = blockIdx.y * 128;
    const int t  = threadIdx.x;
    const int ty = t >> 4, tx = t & 15;

    float acc[8][8];
#pragma unroll
    for (int i = 0; i < 8; i++)
#pragma unroll
        for (int j = 0; j < 8; j++) acc[i][j] = 0.f;

    for (int k0 = 0; k0 < C_; k0 += 16) {
        __syncthreads();
#pragma unroll
        for (int l = 0; l < 2; l++) {
            int row = l * 64 + (t >> 2);
            int k4  = (t & 3) * 4;
            float4 av = make_float4(0.f, 0.f, 0.f, 0.f);
            int m = m0 + row;
            if (m < NTOK) av = *(const float4*)(a + (size_t)m * C_ + k0 + k4);
            As[k4+0][row] = av.x; As[k4+1][row] = av.y;
            As[k4+2][row] = av.z; As[k4+3][row] = av.w;
            float4 bv = *(const float4*)(w + (size_t)(c0 + row) * C_ + k0 + k4);
            Bs[k4+0][row] = bv.x; Bs[k4+1][row] = bv.y;
            Bs[k4+2][row] = bv.z; Bs[k4+3][row] = bv.w;
        }
        __syncthreads();
#pragma unroll
        for (int kk = 0; kk < 16; kk++) {
            float av[8], bv[8];
            *(float4*)(av)     = *(float4*)&As[kk][ty*8];
            *(float4*)(av + 4) = *(float4*)&As[kk][ty*8 + 4];
            *(float4*)(bv)     = *(float4*)&Bs[kk][tx*8];
            *(float4*)(bv + 4) = *(float4*)&Bs[kk][tx*8 + 4];
#pragma unroll
            for (int i = 0; i < 8; i++)
#pragma unroll
                for (int j = 0; j < 8; j++) acc[i][j] += av[i] * bv[j];
        }
    }

    int cb = c0 + tx * 8;
    float pb[8];
    *(float4*)(pb)     = *(const float4*)(bias + cb);
    *(float4*)(pb + 4) = *(const float4*)(bias + cb + 4);
#pragma unroll
    for (int i = 0; i < 8; i++) {
        int m = m0 + ty * 8 + i;
        if (m >= NTOK) break;
        float* p = out + (size_t)m * C_ + cb;
        float4 v0 = make_float4(acc[i][0]+pb[0], acc[i][1]+pb[1], acc[i][2]+pb[2], acc[i][3]+pb[3]);
        float4 v1 = make_float4(acc[i][4]+pb[4], acc[i][5]+pb[5], acc[i][6]+pb[6], acc[i][7]+pb[7]);
        *(float4*)p       = v0;
        *(float4*)(p + 4) = v1;
    }
}

extern "C" void kernel_launch(void* const* d_in, const int* in_sizes, int n_in,
                              void* d_out, int out_size, void* d_ws, size_t ws_size,
                              hipStream_t stream) {
    const float* x      = (const float*)d_in[0];
    const float* qkv_w  = (const float*)d_in[1];
    const float* proj_w = (const float*)d_in[2];
    const float* proj_b = (const float*)d_in[3];
    const float* rpe_w  = (const float*)d_in[4];
    float* out = (float*)d_out;

    float* ws = (float*)d_ws;
    float* qb = ws + Q_OFF;
    float* kb = ws + K_OFF;
    float* vb = ws + V_OFF;
    float* ao = ws + AO_OFF;
    unsigned char* bucket = (unsigned char*)d_ws + BUCKET_BYTE_OFF;

    bucket_kernel<<<dim3((N_ * N_ + 255) / 256), 256, 0, stream>>>(bucket);
    qkv_kernel<<<dim3(65, 18), 256, 0, stream>>>(x, qkv_w, qb, kb, vb);
    attn_kernel<<<dim3(33, 96), 256, 0, stream>>>(qb, kb, vb, rpe_w, bucket, ao);
    proj_kernel<<<dim3(65, 6), 256, 0, stream>>>(ao, proj_w, proj_b, out);
}

// Round 2
// 764.250 us; speedup vs baseline: 2.8647x; 2.8647x over previous
//
#include <hip/hip_runtime.h>
#include <math.h>

#define B_    8
#define N_    1025
#define H_    12
#define HD_   64
#define C_    768
#define BH_   (B_*H_)
#define NTOK  (B_*N_)          // 8200
#define SCALE 0.125f

// ws layout (floats)
#define QKV_ELEMS (BH_*N_*HD_)         // 6,297,600
#define Q_OFF   0
#define K_OFF   (QKV_ELEMS)
#define V_OFF   (2*QKV_ELEMS)
#define AO_OFF  (3*QKV_ELEMS)
#define BUCKET_BYTE_OFF ((size_t)4*QKV_ELEMS*4)

typedef __attribute__((ext_vector_type(8))) short s8bf;
typedef __attribute__((ext_vector_type(4))) float v4f;

__device__ __forceinline__ unsigned short f2bf(float x) {
    union { float f; unsigned u; } v; v.f = x;
    unsigned r = v.u + 0x7FFFu + ((v.u >> 16) & 1u);
    return (unsigned short)(r >> 16);
}
__device__ __forceinline__ float bf2f(unsigned short h) {
    union { float f; unsigned u; } v; v.u = ((unsigned)h) << 16;
    return v.f;
}

// ---------------- bucket table (static, matches numpy float64 exactly) ----------------
__global__ void bucket_kernel(unsigned char* __restrict__ bucket) {
    int tid = blockIdx.x * 256 + threadIdx.x;
    if (tid >= N_ * N_) return;
    int i = tid / N_, j = tid % N_;
    int bk;
    if (i < 1 || j < 1) {
        bk = 7;
    } else {
        int pi = i - 1, pj = j - 1;
        int dy = (pi >> 5) - (pj >> 5);
        int dx = (pi & 31) - (pj & 31);
        double dis = rint(sqrt((double)(dy*dy + dx*dx)));
        if (dis <= 1.9) {
            bk = (int)dis;
        } else {
            double t = 1.9 + log(dis / 1.9) / log(15.2 / 1.9) * (3.8 - 1.9);
            double r = rint(t);
            if (r > 3.8) r = 3.8;
            bk = (int)r;
        }
    }
    bucket[tid] = (unsigned char)bk;
}

// ---------------- QKV GEMM: out = x(8200x768) @ qkv_w^T(768x2304) ----------------
__global__ __launch_bounds__(256) void qkv_kernel(
        const float* __restrict__ x, const float* __restrict__ w,
        float* __restrict__ qb, float* __restrict__ kb, float* __restrict__ vb) {
    __shared__ float As[16][132];
    __shared__ float Bs[16][132];
    const int m0 = blockIdx.x * 128;
    const int c0 = blockIdx.y * 128;
    const int t  = threadIdx.x;
    const int ty = t >> 4, tx = t & 15;

    float acc[8][8];
#pragma unroll
    for (int i = 0; i < 8; i++)
#pragma unroll
        for (int j = 0; j < 8; j++) acc[i][j] = 0.f;

    for (int k0 = 0; k0 < C_; k0 += 16) {
        __syncthreads();
#pragma unroll
        for (int l = 0; l < 2; l++) {
            int row = l * 64 + (t >> 2);
            int k4  = (t & 3) * 4;
            float4 av = make_float4(0.f, 0.f, 0.f, 0.f);
            int m = m0 + row;
            if (m < NTOK) av = *(const float4*)(x + (size_t)m * C_ + k0 + k4);
            As[k4+0][row] = av.x; As[k4+1][row] = av.y;
            As[k4+2][row] = av.z; As[k4+3][row] = av.w;
            float4 bv = *(const float4*)(w + (size_t)(c0 + row) * C_ + k0 + k4);
            Bs[k4+0][row] = bv.x; Bs[k4+1][row] = bv.y;
            Bs[k4+2][row] = bv.z; Bs[k4+3][row] = bv.w;
        }
        __syncthreads();
#pragma unroll
        for (int kk = 0; kk < 16; kk++) {
            float a[8], b[8];
            *(float4*)(a)     = *(float4*)&As[kk][ty*8];
            *(float4*)(a + 4) = *(float4*)&As[kk][ty*8 + 4];
            *(float4*)(b)     = *(float4*)&Bs[kk][tx*8];
            *(float4*)(b + 4) = *(float4*)&Bs[kk][tx*8 + 4];
#pragma unroll
            for (int i = 0; i < 8; i++)
#pragma unroll
                for (int j = 0; j < 8; j++) acc[i][j] += a[i] * b[j];
        }
    }

    int cb   = c0 + tx * 8;
    int comp = cb / C_;
    int rem  = cb % C_;
    int h    = rem >> 6, d0 = rem & 63;
    float* dst = (comp == 0) ? qb : ((comp == 1) ? kb : vb);
    float sc = (comp == 0) ? SCALE : 1.0f;
#pragma unroll
    for (int i = 0; i < 8; i++) {
        int m = m0 + ty * 8 + i;
        if (m >= NTOK) break;
        unsigned um = (unsigned)m;
        int b = um / (unsigned)N_, n = um % (unsigned)N_;
        float* p = dst + ((size_t)((b * H_ + h) * N_ + n)) * HD_ + d0;
        float4 v0 = make_float4(acc[i][0]*sc, acc[i][1]*sc, acc[i][2]*sc, acc[i][3]*sc);
        float4 v1 = make_float4(acc[i][4]*sc, acc[i][5]*sc, acc[i][6]*sc, acc[i][7]*sc);
        *(float4*)p       = v0;
        *(float4*)(p + 4) = v1;
    }
}

// ---------------- attention: bf16 MFMA flash, 64-row Q block, 64-col K tiles ----------------
#define LDT  72     // bf16 stride: 144 B rows (16B-aligned, 4-bank shift -> 2-way = free)
#define LUTS 9

__global__ __launch_bounds__(256) void attn_kernel(
        const float* __restrict__ qb, const float* __restrict__ kb,
        const float* __restrict__ vb, const float* __restrict__ rpe,
        const unsigned char* __restrict__ bucket, float* __restrict__ ao) {
    __shared__ __align__(16) unsigned short Qs[64*LDT];
    __shared__ __align__(16) unsigned short Ks[64*LDT];
    __shared__ __align__(16) unsigned short Vt[64*LDT];   // V transposed: Vt[d][j]
    __shared__ __align__(16) unsigned short Ps[64*LDT];
    __shared__ float lut[64*LUTS];

    const int it = blockIdx.x, bh = blockIdx.y;
    const int b  = bh / H_, h = bh % H_;
    const int i0 = it * 64;
    const int t  = threadIdx.x;
    const int w  = t >> 6;
    const int lane = t & 63;
    const int lc = lane & 15, lq = lane >> 4;

    const float* qp = qb + (size_t)bh * N_ * HD_;
    const float* kp = kb + (size_t)bh * N_ * HD_;
    const float* vp = vb + (size_t)bh * N_ * HD_;

    // ---- stage Q (bf16 row-major, zero rows >= N) ----
    {
        int row = t >> 2, d0 = (t & 3) * 16;
        int gi = i0 + row;
        float buf[16];
        if (gi < N_) {
            *(float4*)(buf)      = *(const float4*)(qp + (size_t)gi * HD_ + d0);
            *(float4*)(buf + 4)  = *(const float4*)(qp + (size_t)gi * HD_ + d0 + 4);
            *(float4*)(buf + 8)  = *(const float4*)(qp + (size_t)gi * HD_ + d0 + 8);
            *(float4*)(buf + 12) = *(const float4*)(qp + (size_t)gi * HD_ + d0 + 12);
        } else {
#pragma unroll
            for (int u = 0; u < 16; u++) buf[u] = 0.f;
        }
        __align__(16) unsigned short hb[16];
#pragma unroll
        for (int u = 0; u < 16; u++) hb[u] = f2bf(buf[u]);
        *(s8bf*)&Qs[row*LDT + d0]     = *(s8bf*)hb;
        *(s8bf*)&Qs[row*LDT + d0 + 8] = *(s8bf*)(hb + 8);
    }
    __syncthreads();

    // ---- lut[row][m] = q_row . rpe[:,m] ----
#pragma unroll
    for (int p = 0; p < 2; p++) {
        int idx = p * 256 + t;
        int row = idx >> 3, m = idx & 7;
        float s = 0.f;
#pragma unroll 8
        for (int d = 0; d < 64; d++) s += bf2f(Qs[row*LDT + d]) * rpe[d*8 + m];
        lut[row*LUTS + m] = s;
    }

    // ---- Q A-fragments, held in registers for all K-tiles ----
    s8bf qf0 = *(s8bf*)&Qs[(w*16 + lc)*LDT + lq*8];
    s8bf qf1 = *(s8bf*)&Qs[(w*16 + lc)*LDT + 32 + lq*8];

    v4f o[4];
#pragma unroll
    for (int dt = 0; dt < 4; dt++) o[dt] = (v4f){0.f, 0.f, 0.f, 0.f};
    float mrow[4], lrow[4];
#pragma unroll
    for (int r = 0; r < 4; r++) { mrow[r] = -INFINITY; lrow[r] = 0.f; }

    const int row_l = w*16 + lq*4;   // + r = local query row of this lane's C-regs

    for (int j0 = 0; j0 < N_; j0 += 64) {
        __syncthreads();   // previous tile's LDS reads complete
        // ---- stage K (bf16 row-major) ----
        {
            int row = t >> 2, d0 = (t & 3) * 16;
            int gj = j0 + row;
            float buf[16];
            if (gj < N_) {
                *(float4*)(buf)      = *(const float4*)(kp + (size_t)gj * HD_ + d0);
                *(float4*)(buf + 4)  = *(const float4*)(kp + (size_t)gj * HD_ + d0 + 4);
                *(float4*)(buf + 8)  = *(const float4*)(kp + (size_t)gj * HD_ + d0 + 8);
                *(float4*)(buf + 12) = *(const float4*)(kp + (size_t)gj * HD_ + d0 + 12);
            } else {
#pragma unroll
                for (int u = 0; u < 16; u++) buf[u] = 0.f;
            }
            __align__(16) unsigned short hb[16];
#pragma unroll
            for (int u = 0; u < 16; u++) hb[u] = f2bf(buf[u]);
            *(s8bf*)&Ks[row*LDT + d0]     = *(s8bf*)hb;
            *(s8bf*)&Ks[row*LDT + d0 + 8] = *(s8bf*)(hb + 8);
        }
        // ---- stage V transposed (Vt[d][j]), d-strided to avoid write conflicts ----
        {
            int jp = t >> 3, dl = t & 7;
            int gj0 = j0 + 2*jp, gj1 = gj0 + 1;
#pragma unroll
            for (int dd = 0; dd < 8; dd++) {
                int d = dl + 8*dd;
                float va = (gj0 < N_) ? vp[(size_t)gj0 * HD_ + d] : 0.f;
                float vb2 = (gj1 < N_) ? vp[(size_t)gj1 * HD_ + d] : 0.f;
                unsigned pk = (unsigned)f2bf(va) | ((unsigned)f2bf(vb2) << 16);
                *(unsigned*)&Vt[d*LDT + 2*jp] = pk;
            }
        }
        __syncthreads();

        // ---- S = Q K^T over 4 column tiles ----
        v4f acc[4];
#pragma unroll
        for (int t4 = 0; t4 < 4; t4++) acc[t4] = (v4f){0.f, 0.f, 0.f, 0.f};
#pragma unroll
        for (int t4 = 0; t4 < 4; t4++) {
            s8bf kf0 = *(s8bf*)&Ks[(t4*16 + lc)*LDT + lq*8];
            s8bf kf1 = *(s8bf*)&Ks[(t4*16 + lc)*LDT + 32 + lq*8];
            acc[t4] = __builtin_amdgcn_mfma_f32_16x16x32_bf16(qf0, kf0, acc[t4], 0, 0, 0);
            acc[t4] = __builtin_amdgcn_mfma_f32_16x16x32_bf16(qf1, kf1, acc[t4], 0, 0, 0);
        }

        // ---- bias (bucket gather -> lut) + column mask ----
#pragma unroll
        for (int t4 = 0; t4 < 4; t4++) {
            int j = j0 + t4*16 + lc;
            bool valid = (j < N_);
            int jb = valid ? j : (N_ - 1);
#pragma unroll
            for (int r = 0; r < 4; r++) {
                int i = i0 + row_l + r;
                int ib = (i < N_) ? i : (N_ - 1);
                int bk = bucket[(size_t)ib * N_ + jb];
                float s = acc[t4][r] + lut[(row_l + r)*LUTS + bk];
                acc[t4][r] = valid ? s : -INFINITY;
            }
        }

        // ---- online softmax (per r; rows duplicated across the 16 lanes of a quad) ----
        float alpha[4];
#pragma unroll
        for (int r = 0; r < 4; r++) {
            float mx = fmaxf(fmaxf(acc[0][r], acc[1][r]), fmaxf(acc[2][r], acc[3][r]));
            mx = fmaxf(mx, __shfl_xor(mx, 1));
            mx = fmaxf(mx, __shfl_xor(mx, 2));
            mx = fmaxf(mx, __shfl_xor(mx, 4));
            mx = fmaxf(mx, __shfl_xor(mx, 8));
            float mn = fmaxf(mrow[r], mx);
            alpha[r] = __expf(mrow[r] - mn);
            mrow[r] = mn;
            float sum = 0.f;
#pragma unroll
            for (int t4 = 0; t4 < 4; t4++) {
                float p = __expf(acc[t4][r] - mn);
                acc[t4][r] = p;
                sum += p;
            }
            sum += __shfl_xor(sum, 1);
            sum += __shfl_xor(sum, 2);
            sum += __shfl_xor(sum, 4);
            sum += __shfl_xor(sum, 8);
            lrow[r] = lrow[r]*alpha[r] + sum;
        }

        // ---- write P (bf16, row-major; per-wave strip so no barrier needed) ----
#pragma unroll
        for (int t4 = 0; t4 < 4; t4++)
#pragma unroll
            for (int r = 0; r < 4; r++)
                Ps[(row_l + r)*LDT + t4*16 + lc] = f2bf(acc[t4][r]);

        // ---- rescale O, then O += P V ----
#pragma unroll
        for (int dt = 0; dt < 4; dt++)
#pragma unroll
            for (int r = 0; r < 4; r++) o[dt][r] *= alpha[r];

        s8bf pf0 = *(s8bf*)&Ps[(w*16 + lc)*LDT + lq*8];
        s8bf pf1 = *(s8bf*)&Ps[(w*16 + lc)*LDT + 32 + lq*8];
#pragma unroll
        for (int dt = 0; dt < 4; dt++) {
            s8bf vf0 = *(s8bf*)&Vt[(dt*16 + lc)*LDT + lq*8];
            s8bf vf1 = *(s8bf*)&Vt[(dt*16 + lc)*LDT + 32 + lq*8];
            o[dt] = __builtin_amdgcn_mfma_f32_16x16x32_bf16(pf0, vf0, o[dt], 0, 0, 0);
            o[dt] = __builtin_amdgcn_mfma_f32_16x16x32_bf16(pf1, vf1, o[dt], 0, 0, 0);
        }
    }

    // ---- epilogue: O / l -> ao (B, N, C) layout ----
#pragma unroll
    for (int r = 0; r < 4; r++) {
        int i = i0 + row_l + r;
        if (i < N_) {
            float inv = 1.0f / lrow[r];
#pragma unroll
            for (int dt = 0; dt < 4; dt++)
                ao[((size_t)(b*N_ + i))*C_ + h*HD_ + dt*16 + lc] = o[dt][r] * inv;
        }
    }
}

// ---------------- proj GEMM: out = ao(8200x768) @ proj_w^T(768x768) + proj_b ----------------
__global__ __launch_bounds__(256) void proj_kernel(
        const float* __restrict__ a, const float* __restrict__ w,
        const float* __restrict__ bias, float* __restrict__ out) {
    __shared__ float As[16][132];
    __shared__ float Bs[16][132];
    const int m0 = blockIdx.x * 128;
    const int c0 = blockIdx.y * 128;
    const int t  = threadIdx.x;
    const int ty = t >> 4, tx = t & 15;

    float acc[8][8];
#pragma unroll
    for (int i = 0; i < 8; i++)
#pragma unroll
        for (int j = 0; j < 8; j++) acc[i][j] = 0.f;

    for (int k0 = 0; k0 < C_; k0 += 16) {
        __syncthreads();
#pragma unroll
        for (int l = 0; l < 2; l++) {
            int row = l * 64 + (t >> 2);
            int k4  = (t & 3) * 4;
            float4 av = make_float4(0.f, 0.f, 0.f, 0.f);
            int m = m0 + row;
            if (m < NTOK) av = *(const float4*)(a + (size_t)m * C_ + k0 + k4);
            As[k4+0][row] = av.x; As[k4+1][row] = av.y;
            As[k4+2][row] = av.z; As[k4+3][row] = av.w;
            float4 bv = *(const float4*)(w + (size_t)(c0 + row) * C_ + k0 + k4);
            Bs[k4+0][row] = bv.x; Bs[k4+1][row] = bv.y;
            Bs[k4+2][row] = bv.z; Bs[k4+3][row] = bv.w;
        }
        __syncthreads();
#pragma unroll
        for (int kk = 0; kk < 16; kk++) {
            float av[8], bv[8];
            *(float4*)(av)     = *(float4*)&As[kk][ty*8];
            *(float4*)(av + 4) = *(float4*)&As[kk][ty*8 + 4];
            *(float4*)(bv)     = *(float4*)&Bs[kk][tx*8];
            *(float4*)(bv + 4) = *(float4*)&Bs[kk][tx*8 + 4];
#pragma unroll
            for (int i = 0; i < 8; i++)
#pragma unroll
                for (int j = 0; j < 8; j++) acc[i][j] += av[i] * bv[j];
        }
    }

    int cb = c0 + tx * 8;
    float pb[8];
    *(float4*)(pb)     = *(const float4*)(bias + cb);
    *(float4*)(pb + 4) = *(const float4*)(bias + cb + 4);
#pragma unroll
    for (int i = 0; i < 8; i++) {
        int m = m0 + ty * 8 + i;
        if (m >= NTOK) break;
        float* p = out + (size_t)m * C_ + cb;
        float4 v0 = make_float4(acc[i][0]+pb[0], acc[i][1]+pb[1], acc[i][2]+pb[2], acc[i][3]+pb[3]);
        float4 v1 = make_float4(acc[i][4]+pb[4], acc[i][5]+pb[5], acc[i][6]+pb[6], acc[i][7]+pb[7]);
        *(float4*)p       = v0;
        *(float4*)(p + 4) = v1;
    }
}

extern "C" void kernel_launch(void* const* d_in, const int* in_sizes, int n_in,
                              void* d_out, int out_size, void* d_ws, size_t ws_size,
                              hipStream_t stream) {
    const float* x      = (const float*)d_in[0];
    const float* qkv_w  = (const float*)d_in[1];
    const float* proj_w = (const float*)d_in[2];
    const float* proj_b = (const float*)d_in[3];
    const float* rpe_w  = (const float*)d_in[4];
    float* out = (float*)d_out;

    float* ws = (float*)d_ws;
    float* qb = ws + Q_OFF;
    float* kb = ws + K_OFF;
    float* vb = ws + V_OFF;
    float* ao = ws + AO_OFF;
    unsigned char* bucket = (unsigned char*)d_ws + BUCKET_BYTE_OFF;

    bucket_kernel<<<dim3((N_ * N_ + 255) / 256), 256, 0, stream>>>(bucket);
    qkv_kernel<<<dim3(65, 18), 256, 0, stream>>>(x, qkv_w, qb, kb, vb);
    attn_kernel<<<dim3(17, 96), 256, 0, stream>>>(qb, kb, vb, rpe_w, bucket, ao);
    proj_kernel<<<dim3(65, 6), 256, 0, stream>>>(ao, proj_w, proj_b, out);
}

// Round 3
// 353.438 us; speedup vs baseline: 6.1944x; 2.1623x over previous
//
#include <hip/hip_runtime.h>
#include <math.h>

#define B_    8
#define N_    1025
#define H_    12
#define HD_   64
#define C_    768
#define BH_   (B_*H_)
#define NTOK  (B_*N_)          // 8200
#define SCALE 0.125f

#define QKV_ELEMS (BH_*N_*HD_)         // 6,297,600

// ws layout (bytes)
#define XB_OFF_B     ((size_t)0)
#define WQKV_OFF_B   (XB_OFF_B + (size_t)NTOK*C_*2)
#define WPROJ_OFF_B  (WQKV_OFF_B + (size_t)3*C_*C_*2)
#define QB_OFF_B     (WPROJ_OFF_B + (size_t)C_*C_*2)
#define KB_OFF_B     (QB_OFF_B + (size_t)QKV_ELEMS*2)
#define VB_OFF_B     (KB_OFF_B + (size_t)QKV_ELEMS*2)
#define AOB_OFF_B    (VB_OFF_B + (size_t)QKV_ELEMS*2)
#define BUCKET_OFF_B (AOB_OFF_B + (size_t)QKV_ELEMS*2)

typedef __attribute__((ext_vector_type(8))) short s8bf;
typedef __attribute__((ext_vector_type(8))) unsigned short u8s;
typedef __attribute__((ext_vector_type(4))) float v4f;
typedef unsigned short ushort_t;

__device__ __forceinline__ unsigned short f2bf(float x) {
    union { float f; unsigned u; } v; v.f = x;
    unsigned r = v.u + 0x7FFFu + ((v.u >> 16) & 1u);
    return (unsigned short)(r >> 16);
}
__device__ __forceinline__ float bf2f(unsigned short h) {
    union { float f; unsigned u; } v; v.u = ((unsigned)h) << 16;
    return v.f;
}

// ---------------- bucket table (static, matches numpy float64 exactly) ----------------
__global__ void bucket_kernel(unsigned char* __restrict__ bucket) {
    int tid = blockIdx.x * 256 + threadIdx.x;
    if (tid >= N_ * N_) return;
    int i = tid / N_, j = tid % N_;
    int bk;
    if (i < 1 || j < 1) {
        bk = 7;
    } else {
        int pi = i - 1, pj = j - 1;
        int dy = (pi >> 5) - (pj >> 5);
        int dx = (pi & 31) - (pj & 31);
        double dis = rint(sqrt((double)(dy*dy + dx*dx)));
        if (dis <= 1.9) {
            bk = (int)dis;
        } else {
            double t = 1.9 + log(dis / 1.9) / log(15.2 / 1.9) * (3.8 - 1.9);
            double r = rint(t);
            if (r > 3.8) r = 3.8;
            bk = (int)r;
        }
    }
    bucket[tid] = (unsigned char)bk;
}

// ---------------- fused f32 -> bf16 cast (x, qkv_w, proj_w) ----------------
__global__ __launch_bounds__(256) void cast_kernel(
        const float* __restrict__ x, const float* __restrict__ w1,
        const float* __restrict__ w2,
        ushort_t* __restrict__ xb, ushort_t* __restrict__ w1b,
        ushort_t* __restrict__ w2b) {
    const int NX = NTOK * C_ / 8, NW1 = 3 * C_ * C_ / 8, NW2 = C_ * C_ / 8;
    int g = blockIdx.x * 256 + threadIdx.x;
    const float* src; ushort_t* dst; int idx;
    if (g < NX)                 { src = x;  dst = xb;  idx = g; }
    else if (g < NX + NW1)      { src = w1; dst = w1b; idx = g - NX; }
    else if (g < NX + NW1 + NW2){ src = w2; dst = w2b; idx = g - NX - NW1; }
    else return;
    size_t off = (size_t)idx * 8;
    float4 a = *(const float4*)(src + off);
    float4 c = *(const float4*)(src + off + 4);
    __align__(16) ushort_t h[8] = {f2bf(a.x), f2bf(a.y), f2bf(a.z), f2bf(a.w),
                                   f2bf(c.x), f2bf(c.y), f2bf(c.z), f2bf(c.w)};
    *(u8s*)(dst + off) = *(u8s*)h;
}

// ---------------- bf16 MFMA GEMM core: 128x128 tile, BK=64, 4 waves x (4x4) 16x16 ----------------
#define LDA 72

// QKV: C(8200x2304) = xb @ wb^T; scatter q/k/v bf16 in (b*H+h, n, d)
__global__ __launch_bounds__(256) void qkv_kernel(
        const ushort_t* __restrict__ xb, const ushort_t* __restrict__ wb,
        ushort_t* __restrict__ qb, ushort_t* __restrict__ kb, ushort_t* __restrict__ vb) {
    __shared__ __align__(16) ushort_t As[128*LDA];
    __shared__ __align__(16) ushort_t Bs[128*LDA];
    const int m0 = blockIdx.x * 128, c0 = blockIdx.y * 128;
    const int t = threadIdx.x;
    const int w = t >> 6, lane = t & 63, lc = lane & 15, lq = lane >> 4;
    const int wm = (w >> 1) * 64, wn = (w & 1) * 64;

    v4f acc[4][4];
#pragma unroll
    for (int mt = 0; mt < 4; mt++)
#pragma unroll
        for (int nt = 0; nt < 4; nt++) acc[mt][nt] = (v4f){0.f, 0.f, 0.f, 0.f};

    for (int k0 = 0; k0 < C_; k0 += 64) {
        __syncthreads();
        const int col = (t & 7) * 8;
#pragma unroll
        for (int itr = 0; itr < 4; itr++) {
            int row = (t >> 3) + 32 * itr;
            int m = m0 + row;
            u8s av = (u8s)0;
            if (m < NTOK) av = *(const u8s*)(xb + (size_t)m * C_ + k0 + col);
            *(u8s*)&As[row * LDA + col] = av;
            u8s bv = *(const u8s*)(wb + (size_t)(c0 + row) * C_ + k0 + col);
            *(u8s*)&Bs[row * LDA + col] = bv;
        }
        __syncthreads();
#pragma unroll
        for (int kk = 0; kk < 64; kk += 32) {
            s8bf af[4], bf[4];
#pragma unroll
            for (int mt = 0; mt < 4; mt++)
                af[mt] = *(s8bf*)&As[(wm + mt*16 + lc) * LDA + kk + lq*8];
#pragma unroll
            for (int nt = 0; nt < 4; nt++)
                bf[nt] = *(s8bf*)&Bs[(wn + nt*16 + lc) * LDA + kk + lq*8];
#pragma unroll
            for (int mt = 0; mt < 4; mt++)
#pragma unroll
                for (int nt = 0; nt < 4; nt++)
                    acc[mt][nt] = __builtin_amdgcn_mfma_f32_16x16x32_bf16(af[mt], bf[nt], acc[mt][nt], 0, 0, 0);
        }
    }

#pragma unroll
    for (int mt = 0; mt < 4; mt++) {
#pragma unroll
        for (int r = 0; r < 4; r++) {
            int m = m0 + wm + mt*16 + lq*4 + r;
            if (m >= NTOK) continue;
            unsigned um = (unsigned)m;
            int b = um / (unsigned)N_, n = um % (unsigned)N_;
#pragma unroll
            for (int nt = 0; nt < 4; nt++) {
                int c = c0 + wn + nt*16 + lc;
                int comp = c / C_, rem = c % C_;
                int h = rem >> 6, d0 = rem & 63;
                ushort_t* dst = (comp == 0) ? qb : ((comp == 1) ? kb : vb);
                float val = acc[mt][nt][r] * ((comp == 0) ? SCALE : 1.0f);
                dst[((size_t)((b*H_ + h)*N_ + n))*HD_ + d0] = f2bf(val);
            }
        }
    }
}

// ---------------- attention: bf16 MFMA flash, 64-row Q block, 64-col K tiles ----------------
#define LDT  72
#define LUTS 9

__global__ __launch_bounds__(256) void attn_kernel(
        const ushort_t* __restrict__ qb, const ushort_t* __restrict__ kb,
        const ushort_t* __restrict__ vb, const float* __restrict__ rpe,
        const unsigned char* __restrict__ bucket, ushort_t* __restrict__ ao) {
    __shared__ __align__(16) ushort_t Qs[64*LDT];
    __shared__ __align__(16) ushort_t Ks[64*LDT];
    __shared__ __align__(16) ushort_t Vt[64*LDT];   // V transposed: Vt[d][j]
    __shared__ __align__(16) ushort_t Ps[64*LDT];
    __shared__ float lut[64*LUTS];

    const int it = blockIdx.x, bh = blockIdx.y;
    const int b  = bh / H_, h = bh % H_;
    const int i0 = it * 64;
    const int t  = threadIdx.x;
    const int w  = t >> 6;
    const int lane = t & 63;
    const int lc = lane & 15, lq = lane >> 4;

    const ushort_t* qp = qb + (size_t)bh * N_ * HD_;
    const ushort_t* kp = kb + (size_t)bh * N_ * HD_;
    const ushort_t* vp = vb + (size_t)bh * N_ * HD_;

    // ---- stage Q (bf16, zero rows >= N) ----
    {
        int row = t >> 2, d0 = (t & 3) * 16;
        int gi = i0 + row;
        u8s h0 = (u8s)0, h1 = (u8s)0;
        if (gi < N_) {
            h0 = *(const u8s*)(qp + (size_t)gi * HD_ + d0);
            h1 = *(const u8s*)(qp + (size_t)gi * HD_ + d0 + 8);
        }
        *(u8s*)&Qs[row*LDT + d0]     = h0;
        *(u8s*)&Qs[row*LDT + d0 + 8] = h1;
    }
    __syncthreads();

    // ---- lut[row][m] = q_row . rpe[:,m] ----
#pragma unroll
    for (int p = 0; p < 2; p++) {
        int idx = p * 256 + t;
        int row = idx >> 3, m = idx & 7;
        float s = 0.f;
#pragma unroll 8
        for (int d = 0; d < 64; d++) s += bf2f(Qs[row*LDT + d]) * rpe[d*8 + m];
        lut[row*LUTS + m] = s;
    }

    s8bf qf0 = *(s8bf*)&Qs[(w*16 + lc)*LDT + lq*8];
    s8bf qf1 = *(s8bf*)&Qs[(w*16 + lc)*LDT + 32 + lq*8];

    v4f o[4];
#pragma unroll
    for (int dt = 0; dt < 4; dt++) o[dt] = (v4f){0.f, 0.f, 0.f, 0.f};
    float mrow[4], lrow[4];
#pragma unroll
    for (int r = 0; r < 4; r++) { mrow[r] = -INFINITY; lrow[r] = 0.f; }

    const int row_l = w*16 + lq*4;

    for (int j0 = 0; j0 < N_; j0 += 64) {
        __syncthreads();
        // ---- stage K ----
        {
            int row = t >> 2, d0 = (t & 3) * 16;
            int gj = j0 + row;
            u8s h0 = (u8s)0, h1 = (u8s)0;
            if (gj < N_) {
                h0 = *(const u8s*)(kp + (size_t)gj * HD_ + d0);
                h1 = *(const u8s*)(kp + (size_t)gj * HD_ + d0 + 8);
            }
            *(u8s*)&Ks[row*LDT + d0]     = h0;
            *(u8s*)&Ks[row*LDT + d0 + 8] = h1;
        }
        // ---- stage V transposed ----
        {
            int jp = t >> 3, dl = t & 7;
            int gj0 = j0 + 2*jp, gj1 = gj0 + 1;
#pragma unroll
            for (int dd = 0; dd < 8; dd++) {
                int d = dl + 8*dd;
                unsigned va = (gj0 < N_) ? vp[(size_t)gj0 * HD_ + d] : 0;
                unsigned vb2 = (gj1 < N_) ? vp[(size_t)gj1 * HD_ + d] : 0;
                *(unsigned*)&Vt[d*LDT + 2*jp] = va | (vb2 << 16);
            }
        }
        __syncthreads();

        // ---- S = Q K^T ----
        v4f acc[4];
#pragma unroll
        for (int t4 = 0; t4 < 4; t4++) acc[t4] = (v4f){0.f, 0.f, 0.f, 0.f};
#pragma unroll
        for (int t4 = 0; t4 < 4; t4++) {
            s8bf kf0 = *(s8bf*)&Ks[(t4*16 + lc)*LDT + lq*8];
            s8bf kf1 = *(s8bf*)&Ks[(t4*16 + lc)*LDT + 32 + lq*8];
            acc[t4] = __builtin_amdgcn_mfma_f32_16x16x32_bf16(qf0, kf0, acc[t4], 0, 0, 0);
            acc[t4] = __builtin_amdgcn_mfma_f32_16x16x32_bf16(qf1, kf1, acc[t4], 0, 0, 0);
        }

        // ---- bias + mask ----
#pragma unroll
        for (int t4 = 0; t4 < 4; t4++) {
            int j = j0 + t4*16 + lc;
            bool valid = (j < N_);
            int jb = valid ? j : (N_ - 1);
#pragma unroll
            for (int r = 0; r < 4; r++) {
                int i = i0 + row_l + r;
                int ib = (i < N_) ? i : (N_ - 1);
                int bk = bucket[(size_t)ib * N_ + jb];
                float s = acc[t4][r] + lut[(row_l + r)*LUTS + bk];
                acc[t4][r] = valid ? s : -INFINITY;
            }
        }

        // ---- online softmax ----
        float alpha[4];
#pragma unroll
        for (int r = 0; r < 4; r++) {
            float mx = fmaxf(fmaxf(acc[0][r], acc[1][r]), fmaxf(acc[2][r], acc[3][r]));
            mx = fmaxf(mx, __shfl_xor(mx, 1));
            mx = fmaxf(mx, __shfl_xor(mx, 2));
            mx = fmaxf(mx, __shfl_xor(mx, 4));
            mx = fmaxf(mx, __shfl_xor(mx, 8));
            float mn = fmaxf(mrow[r], mx);
            alpha[r] = __expf(mrow[r] - mn);
            mrow[r] = mn;
            float sum = 0.f;
#pragma unroll
            for (int t4 = 0; t4 < 4; t4++) {
                float p = __expf(acc[t4][r] - mn);
                acc[t4][r] = p;
                sum += p;
            }
            sum += __shfl_xor(sum, 1);
            sum += __shfl_xor(sum, 2);
            sum += __shfl_xor(sum, 4);
            sum += __shfl_xor(sum, 8);
            lrow[r] = lrow[r]*alpha[r] + sum;
        }

        // ---- write P (per-wave strip) ----
#pragma unroll
        for (int t4 = 0; t4 < 4; t4++)
#pragma unroll
            for (int r = 0; r < 4; r++)
                Ps[(row_l + r)*LDT + t4*16 + lc] = f2bf(acc[t4][r]);

#pragma unroll
        for (int dt = 0; dt < 4; dt++)
#pragma unroll
            for (int r = 0; r < 4; r++) o[dt][r] *= alpha[r];

        s8bf pf0 = *(s8bf*)&Ps[(w*16 + lc)*LDT + lq*8];
        s8bf pf1 = *(s8bf*)&Ps[(w*16 + lc)*LDT + 32 + lq*8];
#pragma unroll
        for (int dt = 0; dt < 4; dt++) {
            s8bf vf0 = *(s8bf*)&Vt[(dt*16 + lc)*LDT + lq*8];
            s8bf vf1 = *(s8bf*)&Vt[(dt*16 + lc)*LDT + 32 + lq*8];
            o[dt] = __builtin_amdgcn_mfma_f32_16x16x32_bf16(pf0, vf0, o[dt], 0, 0, 0);
            o[dt] = __builtin_amdgcn_mfma_f32_16x16x32_bf16(pf1, vf1, o[dt], 0, 0, 0);
        }
    }

    // ---- epilogue: O/l -> ao bf16 (B, N, C) ----
#pragma unroll
    for (int r = 0; r < 4; r++) {
        int i = i0 + row_l + r;
        if (i < N_) {
            float inv = 1.0f / lrow[r];
#pragma unroll
            for (int dt = 0; dt < 4; dt++)
                ao[((size_t)(b*N_ + i))*C_ + h*HD_ + dt*16 + lc] = f2bf(o[dt][r] * inv);
        }
    }
}

// ---------------- proj: out(8200x768) = aob @ wprojb^T + bias, f32 out ----------------
__global__ __launch_bounds__(256) void proj_kernel(
        const ushort_t* __restrict__ ab, const ushort_t* __restrict__ wb,
        const float* __restrict__ bias, float* __restrict__ out) {
    __shared__ __align__(16) ushort_t As[128*LDA];
    __shared__ __align__(16) ushort_t Bs[128*LDA];
    const int m0 = blockIdx.x * 128, c0 = blockIdx.y * 128;
    const int t = threadIdx.x;
    const int w = t >> 6, lane = t & 63, lc = lane & 15, lq = lane >> 4;
    const int wm = (w >> 1) * 64, wn = (w & 1) * 64;

    v4f acc[4][4];
#pragma unroll
    for (int mt = 0; mt < 4; mt++)
#pragma unroll
        for (int nt = 0; nt < 4; nt++) acc[mt][nt] = (v4f){0.f, 0.f, 0.f, 0.f};

    for (int k0 = 0; k0 < C_; k0 += 64) {
        __syncthreads();
        const int col = (t & 7) * 8;
#pragma unroll
        for (int itr = 0; itr < 4; itr++) {
            int row = (t >> 3) + 32 * itr;
            int m = m0 + row;
            u8s av = (u8s)0;
            if (m < NTOK) av = *(const u8s*)(ab + (size_t)m * C_ + k0 + col);
            *(u8s*)&As[row * LDA + col] = av;
            u8s bv = *(const u8s*)(wb + (size_t)(c0 + row) * C_ + k0 + col);
            *(u8s*)&Bs[row * LDA + col] = bv;
        }
        __syncthreads();
#pragma unroll
        for (int kk = 0; kk < 64; kk += 32) {
            s8bf af[4], bf[4];
#pragma unroll
            for (int mt = 0; mt < 4; mt++)
                af[mt] = *(s8bf*)&As[(wm + mt*16 + lc) * LDA + kk + lq*8];
#pragma unroll
            for (int nt = 0; nt < 4; nt++)
                bf[nt] = *(s8bf*)&Bs[(wn + nt*16 + lc) * LDA + kk + lq*8];
#pragma unroll
            for (int mt = 0; mt < 4; mt++)
#pragma unroll
                for (int nt = 0; nt < 4; nt++)
                    acc[mt][nt] = __builtin_amdgcn_mfma_f32_16x16x32_bf16(af[mt], bf[nt], acc[mt][nt], 0, 0, 0);
        }
    }

    float pb[4];
#pragma unroll
    for (int nt = 0; nt < 4; nt++) pb[nt] = bias[c0 + wn + nt*16 + lc];
#pragma unroll
    for (int mt = 0; mt < 4; mt++) {
#pragma unroll
        for (int r = 0; r < 4; r++) {
            int m = m0 + wm + mt*16 + lq*4 + r;
            if (m >= NTOK) continue;
#pragma unroll
            for (int nt = 0; nt < 4; nt++) {
                int c = c0 + wn + nt*16 + lc;
                out[(size_t)m * C_ + c] = acc[mt][nt][r] + pb[nt];
            }
        }
    }
}

extern "C" void kernel_launch(void* const* d_in, const int* in_sizes, int n_in,
                              void* d_out, int out_size, void* d_ws, size_t ws_size,
                              hipStream_t stream) {
    const float* x      = (const float*)d_in[0];
    const float* qkv_w  = (const float*)d_in[1];
    const float* proj_w = (const float*)d_in[2];
    const float* proj_b = (const float*)d_in[3];
    const float* rpe_w  = (const float*)d_in[4];
    float* out = (float*)d_out;

    char* ws = (char*)d_ws;
    ushort_t* xb   = (ushort_t*)(ws + XB_OFF_B);
    ushort_t* wqkv = (ushort_t*)(ws + WQKV_OFF_B);
    ushort_t* wprj = (ushort_t*)(ws + WPROJ_OFF_B);
    ushort_t* qb   = (ushort_t*)(ws + QB_OFF_B);
    ushort_t* kb   = (ushort_t*)(ws + KB_OFF_B);
    ushort_t* vb   = (ushort_t*)(ws + VB_OFF_B);
    ushort_t* aob  = (ushort_t*)(ws + AOB_OFF_B);
    unsigned char* bucket = (unsigned char*)(ws + BUCKET_OFF_B);

    const int ncast = (NTOK*C_ + 3*C_*C_ + C_*C_) / 8;
    bucket_kernel<<<dim3((N_*N_ + 255)/256), 256, 0, stream>>>(bucket);
    cast_kernel<<<dim3((ncast + 255)/256), 256, 0, stream>>>(x, qkv_w, proj_w, xb, wqkv, wprj);
    qkv_kernel<<<dim3(65, 18), 256, 0, stream>>>(xb, wqkv, qb, kb, vb);
    attn_kernel<<<dim3(17, 96), 256, 0, stream>>>(qb, kb, vb, rpe_w, bucket, aob);
    proj_kernel<<<dim3(65, 6), 256, 0, stream>>>(aob, wprj, proj_b, out);
}

// Round 4
// 323.794 us; speedup vs baseline: 6.7615x; 1.0916x over previous
//
#include <hip/hip_runtime.h>
#include <math.h>

#define B_    8
#define N_    1025
#define H_    12
#define HD_   64
#define C_    768
#define BH_   (B_*H_)
#define NTOK  (B_*N_)          // 8200
#define SCALE 0.125f
#define NPAD  1028             // bucketT row stride (mult of 4)
#define NPADV 1088             // vt row stride (17*64)

#define QKV_ELEMS (BH_*N_*HD_)         // 6,297,600

// ws layout (bytes)
#define XB_OFF_B     ((size_t)0)
#define WQKV_OFF_B   (XB_OFF_B + (size_t)NTOK*C_*2)
#define WPROJ_OFF_B  (WQKV_OFF_B + (size_t)3*C_*C_*2)
#define QB_OFF_B     (WPROJ_OFF_B + (size_t)C_*C_*2)
#define KB_OFF_B     (QB_OFF_B + (size_t)QKV_ELEMS*2)
#define VB_OFF_B     (KB_OFF_B + (size_t)QKV_ELEMS*2)
#define AOB_OFF_B    (VB_OFF_B + (size_t)QKV_ELEMS*2)
#define VT_OFF_B     (AOB_OFF_B + (size_t)QKV_ELEMS*2)
#define BUCKET_OFF_B (VT_OFF_B + (size_t)BH_*HD_*NPADV*2)

typedef __attribute__((ext_vector_type(8))) short s8bf;
typedef __attribute__((ext_vector_type(8))) unsigned short u8s;
typedef __attribute__((ext_vector_type(4))) float v4f;
typedef unsigned short ushort_t;

__device__ __forceinline__ unsigned short f2bf(float x) {
    union { float f; unsigned u; } v; v.f = x;
    unsigned r = v.u + 0x7FFFu + ((v.u >> 16) & 1u);
    return (unsigned short)(r >> 16);
}
__device__ __forceinline__ float bf2f(unsigned short h) {
    union { float f; unsigned u; } v; v.u = ((unsigned)h) << 16;
    return v.f;
}

// ---------------- bucketT[j][i] (symmetric; padded stride, clamped fill) ----------------
__global__ void bucket_kernel(unsigned char* __restrict__ bucketT) {
    int tid = blockIdx.x * 256 + threadIdx.x;
    if (tid >= N_ * NPAD) return;
    unsigned ut = (unsigned)tid;
    int j = ut / (unsigned)NPAD, i = ut % (unsigned)NPAD;
    if (i >= N_) i = N_ - 1;           // pad bytes get a valid (clamped) value
    int bk;
    if (i < 1 || j < 1) {
        bk = 7;
    } else {
        int pi = i - 1, pj = j - 1;
        int dy = (pi >> 5) - (pj >> 5);
        int dx = (pi & 31) - (pj & 31);
        double dis = rint(sqrt((double)(dy*dy + dx*dx)));
        if (dis <= 1.9) {
            bk = (int)dis;
        } else {
            double t = 1.9 + log(dis / 1.9) / log(15.2 / 1.9) * (3.8 - 1.9);
            double r = rint(t);
            if (r > 3.8) r = 3.8;
            bk = (int)r;
        }
    }
    bucketT[tid] = (unsigned char)bk;
}

// ---------------- fused f32 -> bf16 cast (x, qkv_w, proj_w) ----------------
__global__ __launch_bounds__(256) void cast_kernel(
        const float* __restrict__ x, const float* __restrict__ w1,
        const float* __restrict__ w2,
        ushort_t* __restrict__ xb, ushort_t* __restrict__ w1b,
        ushort_t* __restrict__ w2b) {
    const int NX = NTOK * C_ / 8, NW1 = 3 * C_ * C_ / 8, NW2 = C_ * C_ / 8;
    int g = blockIdx.x * 256 + threadIdx.x;
    const float* src; ushort_t* dst; int idx;
    if (g < NX)                 { src = x;  dst = xb;  idx = g; }
    else if (g < NX + NW1)      { src = w1; dst = w1b; idx = g - NX; }
    else if (g < NX + NW1 + NW2){ src = w2; dst = w2b; idx = g - NX - NW1; }
    else return;
    size_t off = (size_t)idx * 8;
    float4 a = *(const float4*)(src + off);
    float4 c = *(const float4*)(src + off + 4);
    __align__(16) ushort_t h[8] = {f2bf(a.x), f2bf(a.y), f2bf(a.z), f2bf(a.w),
                                   f2bf(c.x), f2bf(c.y), f2bf(c.z), f2bf(c.w)};
    *(u8s*)(dst + off) = *(u8s*)h;
}

// ---------------- bf16 MFMA GEMM core: 128x128 tile, BK=64, 4 waves x (4x4) 16x16 ----------------
#define LDA 72

__global__ __launch_bounds__(256) void qkv_kernel(
        const ushort_t* __restrict__ xb, const ushort_t* __restrict__ wb,
        ushort_t* __restrict__ qb, ushort_t* __restrict__ kb, ushort_t* __restrict__ vb) {
    __shared__ __align__(16) ushort_t As[128*LDA];
    __shared__ __align__(16) ushort_t Bs[128*LDA];
    const int m0 = blockIdx.x * 128, c0 = blockIdx.y * 128;
    const int t = threadIdx.x;
    const int w = t >> 6, lane = t & 63, lc = lane & 15, lq = lane >> 4;
    const int wm = (w >> 1) * 64, wn = (w & 1) * 64;

    v4f acc[4][4];
#pragma unroll
    for (int mt = 0; mt < 4; mt++)
#pragma unroll
        for (int nt = 0; nt < 4; nt++) acc[mt][nt] = (v4f){0.f, 0.f, 0.f, 0.f};

    for (int k0 = 0; k0 < C_; k0 += 64) {
        __syncthreads();
        const int col = (t & 7) * 8;
#pragma unroll
        for (int itr = 0; itr < 4; itr++) {
            int row = (t >> 3) + 32 * itr;
            int m = m0 + row;
            u8s av = (u8s)0;
            if (m < NTOK) av = *(const u8s*)(xb + (size_t)m * C_ + k0 + col);
            *(u8s*)&As[row * LDA + col] = av;
            u8s bv = *(const u8s*)(wb + (size_t)(c0 + row) * C_ + k0 + col);
            *(u8s*)&Bs[row * LDA + col] = bv;
        }
        __syncthreads();
#pragma unroll
        for (int kk = 0; kk < 64; kk += 32) {
            s8bf af[4], bf[4];
#pragma unroll
            for (int mt = 0; mt < 4; mt++)
                af[mt] = *(s8bf*)&As[(wm + mt*16 + lc) * LDA + kk + lq*8];
#pragma unroll
            for (int nt = 0; nt < 4; nt++)
                bf[nt] = *(s8bf*)&Bs[(wn + nt*16 + lc) * LDA + kk + lq*8];
#pragma unroll
            for (int mt = 0; mt < 4; mt++)
#pragma unroll
                for (int nt = 0; nt < 4; nt++)
                    acc[mt][nt] = __builtin_amdgcn_mfma_f32_16x16x32_bf16(af[mt], bf[nt], acc[mt][nt], 0, 0, 0);
        }
    }

#pragma unroll
    for (int mt = 0; mt < 4; mt++) {
#pragma unroll
        for (int r = 0; r < 4; r++) {
            int m = m0 + wm + mt*16 + lq*4 + r;
            if (m >= NTOK) continue;
            unsigned um = (unsigned)m;
            int b = um / (unsigned)N_, n = um % (unsigned)N_;
#pragma unroll
            for (int nt = 0; nt < 4; nt++) {
                int c = c0 + wn + nt*16 + lc;
                int comp = c / C_, rem = c % C_;
                int h = rem >> 6, d0 = rem & 63;
                ushort_t* dst = (comp == 0) ? qb : ((comp == 1) ? kb : vb);
                float val = acc[mt][nt][r] * ((comp == 0) ? SCALE : 1.0f);
                dst[((size_t)((b*H_ + h)*N_ + n))*HD_ + d0] = f2bf(val);
            }
        }
    }
}

// ---------------- V transpose: (bh, n, d) -> (bh, d, n) with NPADV stride, zero-padded ----------------
__global__ __launch_bounds__(256) void vtrans_kernel(
        const ushort_t* __restrict__ vb, ushort_t* __restrict__ vt) {
    __shared__ ushort_t Ls[64*72];
    const int it = blockIdx.x, bh = blockIdx.y;
    const int n0 = it * 64;
    const int t = threadIdx.x;
    const int row = t >> 2, c16 = (t & 3) * 16;
    {
        int gn = n0 + row;
        u8s a = (u8s)0, b = (u8s)0;
        if (gn < N_) {
            const ushort_t* src = vb + ((size_t)bh * N_ + gn) * HD_ + c16;
            a = *(const u8s*)src;
            b = *(const u8s*)(src + 8);
        }
        *(u8s*)&Ls[row*72 + c16]     = a;
        *(u8s*)&Ls[row*72 + c16 + 8] = b;
    }
    __syncthreads();
    {
        int d = row;
        __align__(16) ushort_t h[16];
#pragma unroll
        for (int u = 0; u < 16; u++) h[u] = Ls[(c16 + u)*72 + d];
        ushort_t* dst = vt + ((size_t)bh * HD_ + d) * NPADV + n0 + c16;
        *(u8s*)dst       = *(u8s*)h;
        *(u8s*)(dst + 8) = *(u8s*)(h + 8);
    }
}

// ---------------- attention: bf16 MFMA flash, 64-row Q block, 64-col K tiles ----------------
#define LDT  72
#define LUTS 9

__global__ __launch_bounds__(256) void attn_kernel(
        const ushort_t* __restrict__ qb, const ushort_t* __restrict__ kb,
        const ushort_t* __restrict__ vt, const float* __restrict__ rpe,
        const unsigned char* __restrict__ bucketT, ushort_t* __restrict__ ao) {
    __shared__ __align__(16) ushort_t Qs[64*LDT];
    __shared__ __align__(16) ushort_t Ks[64*LDT];
    __shared__ __align__(16) ushort_t Vt[64*LDT];   // Vt[d][j]
    __shared__ __align__(16) ushort_t Ps[64*LDT];
    __shared__ float lut[64*LUTS];

    const int it = blockIdx.x, bh = blockIdx.y;
    const int b  = bh / H_, h = bh % H_;
    const int i0 = it * 64;
    const int t  = threadIdx.x;
    const int w  = t >> 6;
    const int lane = t & 63;
    const int lc = lane & 15, lq = lane >> 4;

    const ushort_t* qp = qb + (size_t)bh * N_ * HD_;
    const ushort_t* kp = kb + (size_t)bh * N_ * HD_;
    const ushort_t* vp = vt + (size_t)bh * HD_ * NPADV;

    // ---- stage Q ----
    {
        int row = t >> 2, d0 = (t & 3) * 16;
        int gi = i0 + row;
        u8s h0 = (u8s)0, h1 = (u8s)0;
        if (gi < N_) {
            h0 = *(const u8s*)(qp + (size_t)gi * HD_ + d0);
            h1 = *(const u8s*)(qp + (size_t)gi * HD_ + d0 + 8);
        }
        *(u8s*)&Qs[row*LDT + d0]     = h0;
        *(u8s*)&Qs[row*LDT + d0 + 8] = h1;
    }
    __syncthreads();

    // ---- lut[row][m] = q_row . rpe[:,m] ----
#pragma unroll
    for (int p = 0; p < 2; p++) {
        int idx = p * 256 + t;
        int row = idx >> 3, m = idx & 7;
        float s = 0.f;
#pragma unroll 8
        for (int d = 0; d < 64; d++) s += bf2f(Qs[row*LDT + d]) * rpe[d*8 + m];
        lut[row*LUTS + m] = s;
    }

    s8bf qf0 = *(s8bf*)&Qs[(w*16 + lc)*LDT + lq*8];
    s8bf qf1 = *(s8bf*)&Qs[(w*16 + lc)*LDT + 32 + lq*8];

    v4f o[4];
#pragma unroll
    for (int dt = 0; dt < 4; dt++) o[dt] = (v4f){0.f, 0.f, 0.f, 0.f};
    float mrow[4], lsum[4];
#pragma unroll
    for (int r = 0; r < 4; r++) { mrow[r] = -INFINITY; lsum[r] = 0.f; }

    const int row_l = w*16 + lq*4;

    for (int j0 = 0; j0 < N_; j0 += 64) {
        // ---- prefetch bucket dwords (4 row-buckets per u32; bucketT stride NPAD, aligned) ----
        unsigned bk4[4];
        bool jvalid[4];
#pragma unroll
        for (int t4 = 0; t4 < 4; t4++) {
            int j = j0 + t4*16 + lc;
            jvalid[t4] = (j < N_);
            int jb = jvalid[t4] ? j : (N_ - 1);
            bk4[t4] = *(const unsigned*)(bucketT + (size_t)jb * NPAD + i0 + row_l);
        }
        __syncthreads();
        // ---- stage K ----
        {
            int row = t >> 2, d0 = (t & 3) * 16;
            int gj = j0 + row;
            u8s h0 = (u8s)0, h1 = (u8s)0;
            if (gj < N_) {
                h0 = *(const u8s*)(kp + (size_t)gj * HD_ + d0);
                h1 = *(const u8s*)(kp + (size_t)gj * HD_ + d0 + 8);
            }
            *(u8s*)&Ks[row*LDT + d0]     = h0;
            *(u8s*)&Ks[row*LDT + d0 + 8] = h1;
        }
        // ---- stage Vt (coalesced; vt pre-transposed, zero-padded cols) ----
        {
            int row = t >> 2, col = (t & 3) * 16;
            const ushort_t* src = vp + (size_t)row * NPADV + j0 + col;
            *(u8s*)&Vt[row*LDT + col]     = *(const u8s*)src;
            *(u8s*)&Vt[row*LDT + col + 8] = *(const u8s*)(src + 8);
        }
        __syncthreads();

        // ---- S = Q K^T ----
        v4f acc[4];
#pragma unroll
        for (int t4 = 0; t4 < 4; t4++) acc[t4] = (v4f){0.f, 0.f, 0.f, 0.f};
#pragma unroll
        for (int t4 = 0; t4 < 4; t4++) {
            s8bf kf0 = *(s8bf*)&Ks[(t4*16 + lc)*LDT + lq*8];
            s8bf kf1 = *(s8bf*)&Ks[(t4*16 + lc)*LDT + 32 + lq*8];
            acc[t4] = __builtin_amdgcn_mfma_f32_16x16x32_bf16(qf0, kf0, acc[t4], 0, 0, 0);
            acc[t4] = __builtin_amdgcn_mfma_f32_16x16x32_bf16(qf1, kf1, acc[t4], 0, 0, 0);
        }

        // ---- bias + mask ----
#pragma unroll
        for (int t4 = 0; t4 < 4; t4++) {
#pragma unroll
            for (int r = 0; r < 4; r++) {
                int bk = (bk4[t4] >> (8*r)) & 0xFF;
                float s = acc[t4][r] + lut[(row_l + r)*LUTS + bk];
                acc[t4][r] = jvalid[t4] ? s : -INFINITY;
            }
        }

        // ---- online softmax (deferred l-sum reduction) ----
        float alpha[4];
#pragma unroll
        for (int r = 0; r < 4; r++) {
            float mx = fmaxf(fmaxf(acc[0][r], acc[1][r]), fmaxf(acc[2][r], acc[3][r]));
            mx = fmaxf(mx, __shfl_xor(mx, 1));
            mx = fmaxf(mx, __shfl_xor(mx, 2));
            mx = fmaxf(mx, __shfl_xor(mx, 4));
            mx = fmaxf(mx, __shfl_xor(mx, 8));
            float mn = fmaxf(mrow[r], mx);
            alpha[r] = __expf(mrow[r] - mn);
            mrow[r] = mn;
            float sum = 0.f;
#pragma unroll
            for (int t4 = 0; t4 < 4; t4++) {
                float p = __expf(acc[t4][r] - mn);
                acc[t4][r] = p;
                sum += p;
            }
            lsum[r] = lsum[r]*alpha[r] + sum;
        }

        // ---- write P (per-wave strip) ----
#pragma unroll
        for (int t4 = 0; t4 < 4; t4++)
#pragma unroll
            for (int r = 0; r < 4; r++)
                Ps[(row_l + r)*LDT + t4*16 + lc] = f2bf(acc[t4][r]);

#pragma unroll
        for (int dt = 0; dt < 4; dt++)
#pragma unroll
            for (int r = 0; r < 4; r++) o[dt][r] *= alpha[r];

        s8bf pf0 = *(s8bf*)&Ps[(w*16 + lc)*LDT + lq*8];
        s8bf pf1 = *(s8bf*)&Ps[(w*16 + lc)*LDT + 32 + lq*8];
#pragma unroll
        for (int dt = 0; dt < 4; dt++) {
            s8bf vf0 = *(s8bf*)&Vt[(dt*16 + lc)*LDT + lq*8];
            s8bf vf1 = *(s8bf*)&Vt[(dt*16 + lc)*LDT + 32 + lq*8];
            o[dt] = __builtin_amdgcn_mfma_f32_16x16x32_bf16(pf0, vf0, o[dt], 0, 0, 0);
            o[dt] = __builtin_amdgcn_mfma_f32_16x16x32_bf16(pf1, vf1, o[dt], 0, 0, 0);
        }
    }

    // ---- epilogue: reduce lsum across the 16 row-sharing lanes, store O/l ----
#pragma unroll
    for (int r = 0; r < 4; r++) {
        float s = lsum[r];
        s += __shfl_xor(s, 1);
        s += __shfl_xor(s, 2);
        s += __shfl_xor(s, 4);
        s += __shfl_xor(s, 8);
        int i = i0 + row_l + r;
        if (i < N_) {
            float inv = 1.0f / s;
#pragma unroll
            for (int dt = 0; dt < 4; dt++)
                ao[((size_t)(b*N_ + i))*C_ + h*HD_ + dt*16 + lc] = f2bf(o[dt][r] * inv);
        }
    }
}

// ---------------- proj: out(8200x768) = aob @ wprojb^T + bias, f32 out ----------------
__global__ __launch_bounds__(256) void proj_kernel(
        const ushort_t* __restrict__ ab, const ushort_t* __restrict__ wb,
        const float* __restrict__ bias, float* __restrict__ out) {
    __shared__ __align__(16) ushort_t As[128*LDA];
    __shared__ __align__(16) ushort_t Bs[128*LDA];
    const int m0 = blockIdx.x * 128, c0 = blockIdx.y * 128;
    const int t = threadIdx.x;
    const int w = t >> 6, lane = t & 63, lc = lane & 15, lq = lane >> 4;
    const int wm = (w >> 1) * 64, wn = (w & 1) * 64;

    v4f acc[4][4];
#pragma unroll
    for (int mt = 0; mt < 4; mt++)
#pragma unroll
        for (int nt = 0; nt < 4; nt++) acc[mt][nt] = (v4f){0.f, 0.f, 0.f, 0.f};

    for (int k0 = 0; k0 < C_; k0 += 64) {
        __syncthreads();
        const int col = (t & 7) * 8;
#pragma unroll
        for (int itr = 0; itr < 4; itr++) {
            int row = (t >> 3) + 32 * itr;
            int m = m0 + row;
            u8s av = (u8s)0;
            if (m < NTOK) av = *(const u8s*)(ab + (size_t)m * C_ + k0 + col);
            *(u8s*)&As[row * LDA + col] = av;
            u8s bv = *(const u8s*)(wb + (size_t)(c0 + row) * C_ + k0 + col);
            *(u8s*)&Bs[row * LDA + col] = bv;
        }
        __syncthreads();
#pragma unroll
        for (int kk = 0; kk < 64; kk += 32) {
            s8bf af[4], bf[4];
#pragma unroll
            for (int mt = 0; mt < 4; mt++)
                af[mt] = *(s8bf*)&As[(wm + mt*16 + lc) * LDA + kk + lq*8];
#pragma unroll
            for (int nt = 0; nt < 4; nt++)
                bf[nt] = *(s8bf*)&Bs[(wn + nt*16 + lc) * LDA + kk + lq*8];
#pragma unroll
            for (int mt = 0; mt < 4; mt++)
#pragma unroll
                for (int nt = 0; nt < 4; nt++)
                    acc[mt][nt] = __builtin_amdgcn_mfma_f32_16x16x32_bf16(af[mt], bf[nt], acc[mt][nt], 0, 0, 0);
        }
    }

    float pb[4];
#pragma unroll
    for (int nt = 0; nt < 4; nt++) pb[nt] = bias[c0 + wn + nt*16 + lc];
#pragma unroll
    for (int mt = 0; mt < 4; mt++) {
#pragma unroll
        for (int r = 0; r < 4; r++) {
            int m = m0 + wm + mt*16 + lq*4 + r;
            if (m >= NTOK) continue;
#pragma unroll
            for (int nt = 0; nt < 4; nt++) {
                int c = c0 + wn + nt*16 + lc;
                out[(size_t)m * C_ + c] = acc[mt][nt][r] + pb[nt];
            }
        }
    }
}

extern "C" void kernel_launch(void* const* d_in, const int* in_sizes, int n_in,
                              void* d_out, int out_size, void* d_ws, size_t ws_size,
                              hipStream_t stream) {
    const float* x      = (const float*)d_in[0];
    const float* qkv_w  = (const float*)d_in[1];
    const float* proj_w = (const float*)d_in[2];
    const float* proj_b = (const float*)d_in[3];
    const float* rpe_w  = (const float*)d_in[4];
    float* out = (float*)d_out;

    char* ws = (char*)d_ws;
    ushort_t* xb   = (ushort_t*)(ws + XB_OFF_B);
    ushort_t* wqkv = (ushort_t*)(ws + WQKV_OFF_B);
    ushort_t* wprj = (ushort_t*)(ws + WPROJ_OFF_B);
    ushort_t* qb   = (ushort_t*)(ws + QB_OFF_B);
    ushort_t* kb   = (ushort_t*)(ws + KB_OFF_B);
    ushort_t* vb   = (ushort_t*)(ws + VB_OFF_B);
    ushort_t* aob  = (ushort_t*)(ws + AOB_OFF_B);
    ushort_t* vt   = (ushort_t*)(ws + VT_OFF_B);
    unsigned char* bucketT = (unsigned char*)(ws + BUCKET_OFF_B);

    const int ncast = (NTOK*C_ + 3*C_*C_ + C_*C_) / 8;
    bucket_kernel<<<dim3((N_*NPAD + 255)/256), 256, 0, stream>>>(bucketT);
    cast_kernel<<<dim3((ncast + 255)/256), 256, 0, stream>>>(x, qkv_w, proj_w, xb, wqkv, wprj);
    qkv_kernel<<<dim3(65, 18), 256, 0, stream>>>(xb, wqkv, qb, kb, vb);
    vtrans_kernel<<<dim3(17, 96), 256, 0, stream>>>(vb, vt);
    attn_kernel<<<dim3(17, 96), 256, 0, stream>>>(qb, kb, vt, rpe_w, bucketT, aob);
    proj_kernel<<<dim3(65, 6), 256, 0, stream>>>(aob, wprj, proj_b, out);
}